// Round 1
// baseline (1242.124 us; speedup 1.0000x reference)
//
#include <hip/hip_runtime.h>

#define Hh 64
#define INPUT 3
#define OUTD 2
#define BATCH 1024
#define TENC 512
#define PLEN 300

__device__ __forceinline__ float sigmoidf_(float x) {
    return 1.0f / (1.0f + __expf(-x));
}
__device__ __forceinline__ float tanhfast_(float x) {
    return 2.0f / (1.0f + __expf(-2.0f * x)) - 1.0f;
}
__device__ __forceinline__ float bcast_lane(float v, int lane) {
    return __int_as_float(__builtin_amdgcn_readlane(__float_as_int(v), lane));
}

__global__ __launch_bounds__(256, 4)
void lstm_forecast_kernel(const float* __restrict__ x,
                          const float* __restrict__ force,
                          const float* __restrict__ W_ih,
                          const float* __restrict__ W_hh,
                          const float* __restrict__ b_ih,
                          const float* __restrict__ b_hh,
                          const float* __restrict__ W_out,
                          const float* __restrict__ b_out,
                          float* __restrict__ out)
{
    const int b    = blockIdx.x;
    const int tid  = threadIdx.x;   // gate row j in [0,256)
    const int wave = tid >> 6;      // gate type: 0=i 1=f 2=g 3=o
    const int lane = tid & 63;      // hidden unit u

    __shared__ float x_s[TENC * INPUT];   // 6 KB: this block's input slice
    __shared__ float f_s[PLEN - 1];       // ~1.2 KB: this block's force slice
    __shared__ float g_s[2][4][Hh];       // 2 KB: double-buffered gate strip

    // ---- stage x / force slices into LDS (coalesced) ----
    const float* xb = x + (size_t)b * (TENC * INPUT);
    for (int i = tid; i < TENC * INPUT; i += 256) x_s[i] = xb[i];
    const float* fb = force + (size_t)b * (PLEN - 1);
    for (int i = tid; i < PLEN - 1; i += 256) f_s[i] = fb[i];

    // ---- per-thread persistent weights in VGPRs ----
    float whh[Hh];
    #pragma unroll
    for (int k4 = 0; k4 < Hh / 4; ++k4) {
        const float4 v = *reinterpret_cast<const float4*>(W_hh + (size_t)tid * Hh + k4 * 4);
        whh[k4 * 4 + 0] = v.x; whh[k4 * 4 + 1] = v.y;
        whh[k4 * 4 + 2] = v.z; whh[k4 * 4 + 3] = v.w;
    }
    const float wi0  = W_ih[tid * INPUT + 0];
    const float wi1  = W_ih[tid * INPUT + 1];
    const float wi2  = W_ih[tid * INPUT + 2];
    const float bias = b_ih[tid] + b_hh[tid];

    // output head (lane-indexed rows of W_out)
    const float wo0 = W_out[0 * Hh + lane];
    const float wo1 = W_out[1 * Hh + lane];
    const float bo0 = b_out[0], bo1 = b_out[1];

    float h = 0.0f, c = 0.0f;   // per-wave redundant copy of h[lane], c[lane]
    int   p = 0;                // gate-buffer phase

    __syncthreads();

    // ---- one LSTM step: one barrier, double-buffered gate exchange ----
    auto lstm_step = [&](float x0, float x1, float x2) {
        // h-part first (h in registers, ready immediately); x folded at the end
        float acc0 = bias;
        float acc1 = 0.0f;
        #pragma unroll
        for (int k = 0; k < Hh; k += 2) {
            acc0 = fmaf(whh[k],     bcast_lane(h, k),     acc0);
            acc1 = fmaf(whh[k + 1], bcast_lane(h, k + 1), acc1);
        }
        float acc = acc0 + acc1;
        acc = fmaf(wi0, x0, acc);
        acc = fmaf(wi1, x1, acc);
        acc = fmaf(wi2, x2, acc);

        const float a = (wave == 2) ? tanhfast_(acc) : sigmoidf_(acc);
        g_s[p][wave][lane] = a;
        __syncthreads();
        const float gi = g_s[p][0][lane];
        const float gf = g_s[p][1][lane];
        const float gg = g_s[p][2][lane];
        const float go = g_s[p][3][lane];
        c = fmaf(gf, c, gi * gg);
        h = go * tanhfast_(c);
        p ^= 1;
    };

    // ---- output head: y = W_out @ h + b_out, full-wave butterfly reduce ----
    auto out_head = [&]() -> float2 {
        float p0 = wo0 * h;
        float p1 = wo1 * h;
        #pragma unroll
        for (int m = 32; m >= 1; m >>= 1) {
            p0 += __shfl_xor(p0, m, 64);
            p1 += __shfl_xor(p1, m, 64);
        }
        return make_float2(p0 + bo0, p1 + bo1);
    };

    // ---- encoder ----
    for (int t = 0; t < TENC; ++t) {
        const float x0 = x_s[3 * t + 0];
        const float x1 = x_s[3 * t + 1];
        const float x2 = x_s[3 * t + 2];
        lstm_step(x0, x1, x2);
    }

    float2 y = out_head();
    float* ob = out + (size_t)b * (PLEN * OUTD);
    if (tid == 0) { ob[0] = y.x; ob[1] = y.y; }

    // ---- autoregressive decoder ----
    for (int d = 0; d < PLEN - 1; ++d) {
        const float ft = f_s[d];
        lstm_step(y.x, y.y, ft);
        y = out_head();
        if (tid == 0) { ob[(d + 1) * 2 + 0] = y.x; ob[(d + 1) * 2 + 1] = y.y; }
    }
}

extern "C" void kernel_launch(void* const* d_in, const int* in_sizes, int n_in,
                              void* d_out, int out_size, void* d_ws, size_t ws_size,
                              hipStream_t stream) {
    const float* x     = (const float*)d_in[0];
    const float* force = (const float*)d_in[1];
    const float* W_ih  = (const float*)d_in[2];
    const float* W_hh  = (const float*)d_in[3];
    const float* b_ih  = (const float*)d_in[4];
    const float* b_hh  = (const float*)d_in[5];
    const float* W_out = (const float*)d_in[6];
    const float* b_out = (const float*)d_in[7];
    float* out = (float*)d_out;

    lstm_forecast_kernel<<<BATCH, 256, 0, stream>>>(
        x, force, W_ih, W_hh, b_ih, b_hh, W_out, b_out, out);
}

// Round 2
// 1143.851 us; speedup vs baseline: 1.0859x; 1.0859x over previous
//
#include <hip/hip_runtime.h>

#define Hh 64
#define INPUT 3
#define OUTD 2
#define BATCH 1024
#define TENC 512
#define PLEN 300

#define LOG2E 1.44269504088896340736f

// sigmoid(x) = 1/(1+2^(-x*log2e))
__device__ __forceinline__ float sigm_(float x) {
    float t = __builtin_amdgcn_exp2f(-x * LOG2E);
    return __builtin_amdgcn_rcpf(1.0f + t);
}
// tanh(x) = 1 - 2/(1+2^(2x*log2e))
__device__ __forceinline__ float tanh_(float x) {
    float t = __builtin_amdgcn_exp2f(x * (2.0f * LOG2E));
    return fmaf(-2.0f, __builtin_amdgcn_rcpf(1.0f + t), 1.0f);
}
__device__ __forceinline__ float bl(float v, int lane) {
    return __int_as_float(__builtin_amdgcn_readlane(__float_as_int(v), lane));
}

// 4 MACs against broadcast h[K..K+3]; two independent accumulation chains
#define MAC4(W, K)                               \
    acc0 = fmaf((W).x, bl(h, (K) + 0), acc0);    \
    acc1 = fmaf((W).y, bl(h, (K) + 1), acc1);    \
    acc0 = fmaf((W).z, bl(h, (K) + 2), acc0);    \
    acc1 = fmaf((W).w, bl(h, (K) + 3), acc1);

__global__ __launch_bounds__(256, 4)
void lstm_forecast_kernel(const float* __restrict__ x,
                          const float* __restrict__ force,
                          const float* __restrict__ W_ih,
                          const float* __restrict__ W_hh,
                          const float* __restrict__ b_ih,
                          const float* __restrict__ b_hh,
                          const float* __restrict__ W_out,
                          const float* __restrict__ b_out,
                          float* __restrict__ out)
{
    const int b    = blockIdx.x;
    const int tid  = threadIdx.x;   // gate row j in [0,256)
    const int wave = tid >> 6;      // gate type: 0=i 1=f 2=g 3=o
    const int lane = tid & 63;      // hidden unit u

    __shared__ float x_s[TENC * INPUT];   // 6 KB
    __shared__ float f_s[PLEN - 1];       // ~1.2 KB
    __shared__ float g_s[2][4][Hh];       // 2 KB double-buffered gate strip

    // ---- stage x / force slices into LDS (coalesced) ----
    const float* xb = x + (size_t)b * (TENC * INPUT);
    for (int i = tid; i < TENC * INPUT; i += 256) x_s[i] = xb[i];
    const float* fb = force + (size_t)b * (PLEN - 1);
    for (int i = tid; i < PLEN - 1; i += 256) f_s[i] = fb[i];

    // ---- per-thread weights: 16 NAMED float4 regs (no indexable array) ----
    const float4* wrow = reinterpret_cast<const float4*>(W_hh + (size_t)tid * Hh);
    const float4 w0 = wrow[0],  w1 = wrow[1],  w2 = wrow[2],  w3 = wrow[3];
    const float4 w4 = wrow[4],  w5 = wrow[5],  w6 = wrow[6],  w7 = wrow[7];
    const float4 w8 = wrow[8],  w9 = wrow[9],  wA = wrow[10], wB = wrow[11];
    const float4 wC = wrow[12], wD = wrow[13], wE = wrow[14], wF = wrow[15];

    const float wi0  = W_ih[tid * INPUT + 0];
    const float wi1  = W_ih[tid * INPUT + 1];
    const float wi2  = W_ih[tid * INPUT + 2];
    const float bias = b_ih[tid] + b_hh[tid];

    const float wo0 = W_out[0 * Hh + lane];
    const float wo1 = W_out[1 * Hh + lane];
    const float bo0 = b_out[0], bo1 = b_out[1];

    float h = 0.0f, c = 0.0f;
    int   p = 0;

    __syncthreads();

    auto lstm_step = [&](float x0, float x1, float x2) {
        float acc0 = fmaf(wi0, x0, bias);
        acc0 = fmaf(wi1, x1, acc0);
        acc0 = fmaf(wi2, x2, acc0);
        float acc1 = 0.0f;
        MAC4(w0, 0)  MAC4(w1, 4)  MAC4(w2, 8)  MAC4(w3, 12)
        MAC4(w4, 16) MAC4(w5, 20) MAC4(w6, 24) MAC4(w7, 28)
        MAC4(w8, 32) MAC4(w9, 36) MAC4(wA, 40) MAC4(wB, 44)
        MAC4(wC, 48) MAC4(wD, 52) MAC4(wE, 56) MAC4(wF, 60)
        const float acc = acc0 + acc1;

        const float a = (wave == 2) ? tanh_(acc) : sigm_(acc);
        g_s[p][wave][lane] = a;
        __syncthreads();
        const float gi = g_s[p][0][lane];
        const float gf = g_s[p][1][lane];
        const float gg = g_s[p][2][lane];
        const float go = g_s[p][3][lane];
        c = fmaf(gf, c, gi * gg);
        h = go * tanh_(c);
        p ^= 1;
    };

    auto out_head = [&]() -> float2 {
        float p0 = wo0 * h;
        float p1 = wo1 * h;
        #pragma unroll
        for (int m = 32; m >= 1; m >>= 1) {
            p0 += __shfl_xor(p0, m, 64);
            p1 += __shfl_xor(p1, m, 64);
        }
        return make_float2(p0 + bo0, p1 + bo1);
    };

    // ---- encoder ----
    for (int t = 0; t < TENC; ++t) {
        const float x0 = x_s[3 * t + 0];
        const float x1 = x_s[3 * t + 1];
        const float x2 = x_s[3 * t + 2];
        lstm_step(x0, x1, x2);
    }

    float2 y = out_head();
    float* ob = out + (size_t)b * (PLEN * OUTD);
    if (tid == 0) { ob[0] = y.x; ob[1] = y.y; }

    // ---- autoregressive decoder ----
    for (int d = 0; d < PLEN - 1; ++d) {
        const float ft = f_s[d];
        lstm_step(y.x, y.y, ft);
        y = out_head();
        if (tid == 0) { ob[(d + 1) * 2 + 0] = y.x; ob[(d + 1) * 2 + 1] = y.y; }
    }
}

extern "C" void kernel_launch(void* const* d_in, const int* in_sizes, int n_in,
                              void* d_out, int out_size, void* d_ws, size_t ws_size,
                              hipStream_t stream) {
    const float* x     = (const float*)d_in[0];
    const float* force = (const float*)d_in[1];
    const float* W_ih  = (const float*)d_in[2];
    const float* W_hh  = (const float*)d_in[3];
    const float* b_ih  = (const float*)d_in[4];
    const float* b_hh  = (const float*)d_in[5];
    const float* W_out = (const float*)d_in[6];
    const float* b_out = (const float*)d_in[7];
    float* out = (float*)d_out;

    lstm_forecast_kernel<<<BATCH, 256, 0, stream>>>(
        x, force, W_ih, W_hh, b_ih, b_hh, W_out, b_out, out);
}

// Round 3
// 685.053 us; speedup vs baseline: 1.8132x; 1.6697x over previous
//
#include <hip/hip_runtime.h>

#define Hh 64
#define INPUT 3
#define OUTD 2
#define BATCH 1024
#define TENC 512
#define PLEN 300

#define LOG2E 1.44269504088896340736f

// tanh(x) = 1 - 2/(1+2^(2x*log2e))
__device__ __forceinline__ float tanh_(float x) {
    float t = __builtin_amdgcn_exp2f(x * (2.0f * LOG2E));
    return fmaf(-2.0f, __builtin_amdgcn_rcpf(1.0f + t), 1.0f);
}

// quad-broadcast via DPP: every lane of a quad gets the value of quad-lane Q
#define QUADB(dst, src, pat)                                                   \
    dst = __int_as_float(__builtin_amdgcn_update_dpp(                          \
        0, __float_as_int(src), (pat), 0xF, 0xF, true))

// 4 MACs against h[K..K+3] read from LDS (same-address broadcast, b128)
#define MACQ(W, K)                                                             \
    {                                                                          \
        const float4 hv = *reinterpret_cast<const float4*>(&hb[(K)]);          \
        acc0 = fmaf((W).x, hv.x, acc0);                                        \
        acc1 = fmaf((W).y, hv.y, acc1);                                        \
        acc0 = fmaf((W).z, hv.z, acc0);                                        \
        acc1 = fmaf((W).w, hv.w, acc1);                                        \
    }

#define PIN4(W) asm volatile("" : "+v"((W).x), "+v"((W).y), "+v"((W).z), "+v"((W).w))

__global__ __launch_bounds__(256, 4)
void lstm_forecast_kernel(const float* __restrict__ x,
                          const float* __restrict__ force,
                          const float* __restrict__ W_ih,
                          const float* __restrict__ W_hh,
                          const float* __restrict__ b_ih,
                          const float* __restrict__ b_hh,
                          const float* __restrict__ W_out,
                          const float* __restrict__ b_out,
                          float* __restrict__ out)
{
    const int b    = blockIdx.x;
    const int tid  = threadIdx.x;
    const int u    = tid >> 2;          // hidden unit 0..63
    const int g    = tid & 3;           // gate 0=i 1=f 2=g 3=o (quad-local)
    const int wv   = tid >> 6;          // wave 0..3
    const int lane = tid & 63;
    const int r    = (g << 6) + u;      // row of W_ih/W_hh/bias

    __shared__ __align__(16) float x_s[TENC * INPUT];  // 6 KB
    __shared__ __align__(16) float f_s[PLEN - 1];      // ~1.2 KB
    __shared__ __align__(16) float h_s[2][Hh];         // 512 B double-buffered h
    __shared__ __align__(16) float y_s[2][8];          // per-wave y partials

    // ---- stage x / force slices into LDS (coalesced) ----
    const float* xb = x + (size_t)b * (TENC * INPUT);
    for (int i = tid; i < TENC * INPUT; i += 256) x_s[i] = xb[i];
    const float* fb = force + (size_t)b * (PLEN - 1);
    for (int i = tid; i < PLEN - 1; i += 256) f_s[i] = fb[i];
    if (tid < Hh) h_s[0][tid] = 0.0f;

    // ---- per-thread weights: 16 named float4 (row r of W_hh) ----
    const float4* wrow = reinterpret_cast<const float4*>(W_hh + (size_t)r * Hh);
    float4 w0 = wrow[0],  w1 = wrow[1],  w2 = wrow[2],  w3 = wrow[3];
    float4 w4 = wrow[4],  w5 = wrow[5],  w6 = wrow[6],  w7 = wrow[7];
    float4 w8 = wrow[8],  w9 = wrow[9],  wA = wrow[10], wB = wrow[11];
    float4 wC = wrow[12], wD = wrow[13], wE = wrow[14], wF = wrow[15];
    PIN4(w0); PIN4(w1); PIN4(w2); PIN4(w3);
    PIN4(w4); PIN4(w5); PIN4(w6); PIN4(w7);
    PIN4(w8); PIN4(w9); PIN4(wA); PIN4(wB);
    PIN4(wC); PIN4(wD); PIN4(wE); PIN4(wF);

    const float wi0  = W_ih[r * INPUT + 0];
    const float wi1  = W_ih[r * INPUT + 1];
    const float wi2  = W_ih[r * INPUT + 2];
    const float bias = b_ih[r] + b_hh[r];

    // branch-free activation constants: a = am * rcp(1 + 2^(acc*kmul)) + acK
    const float kmul = (g == 2) ? (-2.0f * LOG2E) : (-LOG2E);
    const float am   = (g == 2) ? 2.0f : 1.0f;
    const float acK  = (g == 2) ? -1.0f : 0.0f;

    // output head: g==0 lanes carry W_out row 0, g==1 lanes row 1
    const float wog = (g == 1) ? W_out[Hh + u] : W_out[u];
    const float bo0 = b_out[0], bo1 = b_out[1];

    float c  = 0.0f;
    int   rp = 0;

    __syncthreads();

    // one LSTM step: MAC from h_s[rp], DPP gate exchange, write h_s[rp^1]
    auto lstm_step = [&](float x0, float x1, float x2, bool do_y) {
        const float* hb = h_s[rp];
        float acc0 = fmaf(wi0, x0, bias);
        float acc1 = fmaf(wi1, x1, 0.0f);
        acc0 = fmaf(wi2, x2, acc0);
        MACQ(w0, 0)  MACQ(w1, 4)  MACQ(w2, 8)  MACQ(w3, 12)
        MACQ(w4, 16) MACQ(w5, 20) MACQ(w6, 24) MACQ(w7, 28)
        MACQ(w8, 32) MACQ(w9, 36) MACQ(wA, 40) MACQ(wB, 44)
        MACQ(wC, 48) MACQ(wD, 52) MACQ(wE, 56) MACQ(wF, 60)
        const float acc = acc0 + acc1;

        // activation (branch-free, per-thread constants)
        const float e  = __builtin_amdgcn_exp2f(acc * kmul);
        const float rr = __builtin_amdgcn_rcpf(1.0f + e);
        const float a  = fmaf(am, rr, acK);

        // gather all 4 gates within the quad (register-only DPP)
        float gi, gf, gg, go;
        QUADB(gi, a, 0x00);   // quad_perm(0,0,0,0)
        QUADB(gf, a, 0x55);   // quad_perm(1,1,1,1)
        QUADB(gg, a, 0xAA);   // quad_perm(2,2,2,2)
        QUADB(go, a, 0xFF);   // quad_perm(3,3,3,3)

        c = fmaf(gf, c, gi * gg);
        const float h = go * tanh_(c);

        if (g == 0) h_s[rp ^ 1][u] = h;

        if (do_y) {
            // y partials: g==0 lanes -> y0, g==1 lanes -> y1, per-wave reduce
            float pp = (g < 2) ? wog * h : 0.0f;
            pp += __shfl_xor(pp, 4, 64);
            pp += __shfl_xor(pp, 8, 64);
            pp += __shfl_xor(pp, 16, 64);
            pp += __shfl_xor(pp, 32, 64);
            if (lane < 2) y_s[rp ^ 1][wv * 2 + lane] = pp;
        }

        rp ^= 1;
        __syncthreads();
    };

    auto read_y = [&]() -> float2 {
        const float4 ya = *reinterpret_cast<const float4*>(&y_s[rp][0]);
        const float4 yb = *reinterpret_cast<const float4*>(&y_s[rp][4]);
        return make_float2(ya.x + ya.z + yb.x + yb.z + bo0,
                           ya.y + ya.w + yb.y + yb.w + bo1);
    };

    // ---- encoder ----
    for (int t = 0; t < TENC - 1; ++t) {
        lstm_step(x_s[3 * t + 0], x_s[3 * t + 1], x_s[3 * t + 2], false);
    }
    lstm_step(x_s[3 * (TENC - 1) + 0], x_s[3 * (TENC - 1) + 1],
              x_s[3 * (TENC - 1) + 2], true);

    float2 y = read_y();
    float* ob = out + (size_t)b * (PLEN * OUTD);
    if (tid == 0) { ob[0] = y.x; ob[1] = y.y; }

    // ---- autoregressive decoder ----
    for (int d = 0; d < PLEN - 1; ++d) {
        lstm_step(y.x, y.y, f_s[d], true);
        y = read_y();
        if (tid == 0) { ob[(d + 1) * 2 + 0] = y.x; ob[(d + 1) * 2 + 1] = y.y; }
    }
}

extern "C" void kernel_launch(void* const* d_in, const int* in_sizes, int n_in,
                              void* d_out, int out_size, void* d_ws, size_t ws_size,
                              hipStream_t stream) {
    const float* x     = (const float*)d_in[0];
    const float* force = (const float*)d_in[1];
    const float* W_ih  = (const float*)d_in[2];
    const float* W_hh  = (const float*)d_in[3];
    const float* b_ih  = (const float*)d_in[4];
    const float* b_hh  = (const float*)d_in[5];
    const float* W_out = (const float*)d_in[6];
    const float* b_out = (const float*)d_in[7];
    float* out = (float*)d_out;

    lstm_forecast_kernel<<<BATCH, 256, 0, stream>>>(
        x, force, W_ih, W_hh, b_ih, b_hh, W_out, b_out, out);
}